// Round 3
// baseline (15.048 us; speedup 1.0000x reference)
//
#include <hip/hip_runtime.h>

constexpr int Q    = 20;
constexpr int EMB  = 64;
constexpr int Bsz  = 16, H = 48, W = 48;
constexpr int HW   = H * W;          // 2304
constexpr int NPIX = Bsz * HW;       // 36864
constexpr int BLOCK = 256;
constexpr int TPP   = 8;             // threads per pixel
constexpr int PIXPB = BLOCK / TPP;   // 32 pixels per block
constexpr int NBLK  = NPIX / PIXPB;  // 1152 blocks

// LDS combined table: 14 coefficient rows + 1 base row.
// rows 0-4  : w2[0]*(T[k]-T[5])        k=0..4   (coef cT[k])
// rows 5-8  : w2[1]*(D[k]-D[4])        k=0..3   (coef cD[k])
// rows 9-12 : w2[2]*(R[k]-R[4])        k=0..3   (coef cR[k])
// row  13   : w2[4]*(P[1]-P[0])                 (coef rep)
// row  14   : sumw1*(w2[0]T5 + w2[1]D4 + w2[2]R4 + w2[4]P0)   (coef 1)
__global__ __launch_bounds__(BLOCK)
void act_pre_kernel(const int* __restrict__ unit,
                    const int* __restrict__ atp,  const int* __restrict__ dirp,
                    const int* __restrict__ resp, const int* __restrict__ repp,
                    const float* __restrict__ amtp, const float* __restrict__ np_,
                    const float* __restrict__ Ttab, const float* __restrict__ Dtab,
                    const float* __restrict__ Rtab, const float* __restrict__ Ptab,
                    const float* __restrict__ w1p,  const float* __restrict__ b1p,
                    const float* __restrict__ w2p,  const float* __restrict__ b2p,
                    float* __restrict__ out)
{
    __shared__ float sc[15][EMB];
    __shared__ float sw1[Q];
    __shared__ float sconst[3];   // w2[3], w2[5], b1*sum(w2)+b2

    const int tid = threadIdx.x;
    for (int i = tid; i < 15 * EMB; i += BLOCK) {
        const int row = i >> 6, e = i & 63;
        float v;
        if (row < 5)       v = w2p[0] * (Ttab[row * EMB + e]       - Ttab[5 * EMB + e]);
        else if (row < 9)  v = w2p[1] * (Dtab[(row - 5) * EMB + e] - Dtab[4 * EMB + e]);
        else if (row < 13) v = w2p[2] * (Rtab[(row - 9) * EMB + e] - Rtab[4 * EMB + e]);
        else if (row == 13) v = w2p[4] * (Ptab[EMB + e] - Ptab[e]);
        else {
            float sumw = 0.f;
            #pragma unroll
            for (int q = 0; q < Q; ++q) sumw += w1p[q];
            v = sumw * (w2p[0] * Ttab[5 * EMB + e] + w2p[1] * Dtab[4 * EMB + e]
                      + w2p[2] * Rtab[4 * EMB + e] + w2p[4] * Ptab[e]);
        }
        sc[row][e] = v;
    }
    if (tid < Q) sw1[tid] = w1p[tid];
    if (tid == 0) {
        sconst[0] = w2p[3];
        sconst[1] = w2p[5];
        const float sumw2 = w2p[0] + w2p[1] + w2p[2] + w2p[3] + w2p[4] + w2p[5];
        sconst[2] = b1p[0] * sumw2 + b2p[0];
    }
    __syncthreads();

    const int pIB = tid >> 3;          // pixel within block (0..31)
    const int t   = tid & 7;           // sub-thread within pixel
    const int pix = blockIdx.x * PIXPB + pIB;

    float cT[5] = {}, cD[4] = {}, cR[4] = {};
    float rep = 0.f, amtAcc = 0.f, nAcc = 0.f;

    if (t < 5) {   // threads 0-4 each own q-group [4t, 4t+4): one aligned vec load per array
        const int base = pix * Q + t * 4;
        const int4   av = *reinterpret_cast<const int4*>(atp  + base);
        const int4   dv = *reinterpret_cast<const int4*>(dirp + base);
        const int4   rv = *reinterpret_cast<const int4*>(resp + base);
        const int4   pv = *reinterpret_cast<const int4*>(repp + base);
        const float4 mv = *reinterpret_cast<const float4*>(amtp + base);
        const float4 nv = *reinterpret_cast<const float4*>(np_  + base);
        const int   ai[4] = {av.x, av.y, av.z, av.w};
        const int   di[4] = {dv.x, dv.y, dv.z, dv.w};
        const int   ri[4] = {rv.x, rv.y, rv.z, rv.w};
        const int   pi[4] = {pv.x, pv.y, pv.z, pv.w};
        const float mf[4] = {mv.x, mv.y, mv.z, mv.w};
        const float nf[4] = {nv.x, nv.y, nv.z, nv.w};
        #pragma unroll
        for (int j = 0; j < 4; ++j) {
            const float wq = sw1[t * 4 + j];
            #pragma unroll
            for (int k = 0; k < 5; ++k) cT[k] += (ai[j] == k) ? wq : 0.f;
            #pragma unroll
            for (int k = 0; k < 4; ++k) cD[k] += (di[j] == k) ? wq : 0.f;
            #pragma unroll
            for (int k = 0; k < 4; ++k) cR[k] += (ri[j] == k) ? wq : 0.f;
            rep    += (pi[j] != 0) ? wq : 0.f;
            amtAcc += wq * mf[j];
            nAcc   += wq * nf[j];
        }
    }

    // --- butterfly allreduce across the 8 threads of this pixel ---
    #define RED8(x) { x += __shfl_xor(x, 1); x += __shfl_xor(x, 2); x += __shfl_xor(x, 4); }
    #pragma unroll
    for (int k = 0; k < 5; ++k) RED8(cT[k]);
    #pragma unroll
    for (int k = 0; k < 4; ++k) RED8(cD[k]);
    #pragma unroll
    for (int k = 0; k < 4; ++k) RED8(cR[k]);
    RED8(rep); RED8(amtAcc); RED8(nAcc);
    #undef RED8

    const float scalar = sconst[0] * amtAcc + sconst[1] * nAcc + sconst[2];
    const float ind = (unit[pix] != 0) ? 1.f : 0.f;

    float coef[14];
    #pragma unroll
    for (int k = 0; k < 5; ++k) coef[k] = cT[k];
    #pragma unroll
    for (int k = 0; k < 4; ++k) coef[5 + k] = cD[k];
    #pragma unroll
    for (int k = 0; k < 4; ++k) coef[9 + k] = cR[k];
    coef[13] = rep;

    const int b  = pix / HW;
    const int hw = pix - b * HW;
    float* outp = out + b * (EMB * HW) + hw;

    // --- each thread computes 8 channels: e in [8t, 8t+8) ---
    #pragma unroll
    for (int i = 0; i < 2; ++i) {
        const int e0 = t * 8 + i * 4;
        const float4 bv = *reinterpret_cast<const float4*>(&sc[14][e0]);
        float va0 = scalar + bv.x, va1 = scalar + bv.y;
        float va2 = scalar + bv.z, va3 = scalar + bv.w;
        #pragma unroll
        for (int k = 0; k < 14; ++k) {
            const float4 sv = *reinterpret_cast<const float4*>(&sc[k][e0]);
            va0 += coef[k] * sv.x;
            va1 += coef[k] * sv.y;
            va2 += coef[k] * sv.z;
            va3 += coef[k] * sv.w;
        }
        va0 = ((va0 >= 0.f) ? va0 : 0.01f * va0) * ind;
        va1 = ((va1 >= 0.f) ? va1 : 0.01f * va1) * ind;
        va2 = ((va2 >= 0.f) ? va2 : 0.01f * va2) * ind;
        va3 = ((va3 >= 0.f) ? va3 : 0.01f * va3) * ind;
        outp[(e0 + 0) * HW] = va0;
        outp[(e0 + 1) * HW] = va1;
        outp[(e0 + 2) * HW] = va2;
        outp[(e0 + 3) * HW] = va3;
    }
}

extern "C" void kernel_launch(void* const* d_in, const int* in_sizes, int n_in,
                              void* d_out, int out_size, void* d_ws, size_t ws_size,
                              hipStream_t stream) {
    const int*   unit = (const int*)  d_in[0];
    const int*   atp  = (const int*)  d_in[1];
    const int*   dirp = (const int*)  d_in[2];
    const int*   resp = (const int*)  d_in[3];
    const int*   repp = (const int*)  d_in[4];
    const float* amtp = (const float*)d_in[5];
    const float* np_  = (const float*)d_in[6];
    const float* Ttab = (const float*)d_in[7];
    const float* Dtab = (const float*)d_in[8];
    const float* Rtab = (const float*)d_in[9];
    const float* Ptab = (const float*)d_in[10];
    const float* w1p  = (const float*)d_in[11];
    const float* b1p  = (const float*)d_in[12];
    const float* w2p  = (const float*)d_in[13];
    const float* b2p  = (const float*)d_in[14];
    float* out = (float*)d_out;

    act_pre_kernel<<<NBLK, BLOCK, 0, stream>>>(
        unit, atp, dirp, resp, repp, amtp, np_,
        Ttab, Dtab, Rtab, Ptab, w1p, b1p, w2p, b2p, out);
}

// Round 4
// 14.198 us; speedup vs baseline: 1.0599x; 1.0599x over previous
//
#include <hip/hip_runtime.h>

constexpr int Q    = 20;
constexpr int EMB  = 64;
constexpr int Bsz  = 16, H = 48, W = 48;
constexpr int HW   = H * W;          // 2304
constexpr int NPIX = Bsz * HW;       // 36864
constexpr int BLOCK = 128;
constexpr int TPP   = 4;             // threads per pixel
constexpr int PIXPB = BLOCK / TPP;   // 32 pixels per block
constexpr int NBLK  = NPIX / PIXPB;  // 1152 blocks

// LDS combined table: 14 coefficient rows + 1 base row.
// rows 0-4  : w2[0]*(T[k]-T[5])        k=0..4   (coef cT[k])
// rows 5-8  : w2[1]*(D[k]-D[4])        k=0..3   (coef cD[k])
// rows 9-12 : w2[2]*(R[k]-R[4])        k=0..3   (coef cR[k])
// row  13   : w2[4]*(P[1]-P[0])                 (coef rep)
// row  14   : sumw1*(w2[0]T5 + w2[1]D4 + w2[2]R4 + w2[4]P0)   (coef 1)
__global__ __launch_bounds__(BLOCK)
void act_pre_kernel(const int* __restrict__ unit,
                    const int* __restrict__ atp,  const int* __restrict__ dirp,
                    const int* __restrict__ resp, const int* __restrict__ repp,
                    const float* __restrict__ amtp, const float* __restrict__ np_,
                    const float* __restrict__ Ttab, const float* __restrict__ Dtab,
                    const float* __restrict__ Rtab, const float* __restrict__ Ptab,
                    const float* __restrict__ w1p,  const float* __restrict__ b1p,
                    const float* __restrict__ w2p,  const float* __restrict__ b2p,
                    float* __restrict__ out)
{
    __shared__ float sc[15][EMB];

    const int tid = threadIdx.x;
    const int pIB = tid >> 2;          // pixel within block (0..31)
    const int t   = tid & 3;           // sub-thread within pixel
    const int pix = blockIdx.x * PIXPB + pIB;

    // ---- issue ALL per-pixel global loads first (overlap table-fill latency) ----
    const int base = pix * Q + t * 4;
    const int4   av = *reinterpret_cast<const int4*>(atp  + base);
    const int4   dv = *reinterpret_cast<const int4*>(dirp + base);
    const int4   rv = *reinterpret_cast<const int4*>(resp + base);
    const int4   pv = *reinterpret_cast<const int4*>(repp + base);
    const float4 mv = *reinterpret_cast<const float4*>(amtp + base);
    const float4 nv = *reinterpret_cast<const float4*>(np_  + base);
    const int tail  = pix * Q + 16 + t;
    const int   as = atp[tail],  ds2 = dirp[tail], rs = resp[tail], ps = repp[tail];
    const float ms = amtp[tail], ns = np_[tail];
    const int   uu = unit[pix];
    const float4 wv = *reinterpret_cast<const float4*>(w1p + t * 4);  // w1[4t..4t+4)
    const float  ws = w1p[16 + t];                                    // w1[16+t]

    // uniform scalars (s_load, L2-hot)
    const float w20 = w2p[0], w21 = w2p[1], w22 = w2p[2];
    const float w23 = w2p[3], w24 = w2p[4], w25 = w2p[5];
    const float constC = b1p[0] * (w20 + w21 + w22 + w23 + w24 + w25) + b2p[0];

    // ---- LDS table fill (its global loads overlap the pixel loads above) ----
    for (int i = tid; i < 15 * EMB; i += BLOCK) {
        const int row = i >> 6, e = i & 63;
        float v;
        if (row < 5)        v = w20 * (Ttab[row * EMB + e]       - Ttab[5 * EMB + e]);
        else if (row < 9)   v = w21 * (Dtab[(row - 5) * EMB + e] - Dtab[4 * EMB + e]);
        else if (row < 13)  v = w22 * (Rtab[(row - 9) * EMB + e] - Rtab[4 * EMB + e]);
        else if (row == 13) v = w24 * (Ptab[EMB + e] - Ptab[e]);
        else {
            float sumw = 0.f;
            #pragma unroll
            for (int q = 0; q < Q; ++q) sumw += w1p[q];
            v = sumw * (w20 * Ttab[5 * EMB + e] + w21 * Dtab[4 * EMB + e]
                      + w22 * Rtab[4 * EMB + e] + w24 * Ptab[e]);
        }
        sc[row][e] = v;
    }

    // ---- coefficient accumulation (register-only; runs before the barrier) ----
    const int   ai[5] = {av.x, av.y, av.z, av.w, as};
    const int   di[5] = {dv.x, dv.y, dv.z, dv.w, ds2};
    const int   ri[5] = {rv.x, rv.y, rv.z, rv.w, rs};
    const int   pi[5] = {pv.x, pv.y, pv.z, pv.w, ps};
    const float mf[5] = {mv.x, mv.y, mv.z, mv.w, ms};
    const float nf[5] = {nv.x, nv.y, nv.z, nv.w, ns};
    const float wf[5] = {wv.x, wv.y, wv.z, wv.w, ws};

    float cT[5] = {}, cD[4] = {}, cR[4] = {};
    float rep = 0.f, amtAcc = 0.f, nAcc = 0.f;
    #pragma unroll
    for (int j = 0; j < 5; ++j) {
        const float wq = wf[j];
        #pragma unroll
        for (int k = 0; k < 5; ++k) cT[k] += (ai[j] == k) ? wq : 0.f;
        #pragma unroll
        for (int k = 0; k < 4; ++k) cD[k] += (di[j] == k) ? wq : 0.f;
        #pragma unroll
        for (int k = 0; k < 4; ++k) cR[k] += (ri[j] == k) ? wq : 0.f;
        rep    += (pi[j] != 0) ? wq : 0.f;
        amtAcc += wq * mf[j];
        nAcc   += wq * nf[j];
    }

    // ---- butterfly allreduce across the 4 threads of this pixel ----
    #define RED4(x) { x += __shfl_xor(x, 1); x += __shfl_xor(x, 2); }
    #pragma unroll
    for (int k = 0; k < 5; ++k) RED4(cT[k]);
    #pragma unroll
    for (int k = 0; k < 4; ++k) RED4(cD[k]);
    #pragma unroll
    for (int k = 0; k < 4; ++k) RED4(cR[k]);
    RED4(rep); RED4(amtAcc); RED4(nAcc);
    #undef RED4

    const float scalar = w23 * amtAcc + w25 * nAcc + constC;
    const float ind = (uu != 0) ? 1.f : 0.f;

    float coef[14];
    #pragma unroll
    for (int k = 0; k < 5; ++k) coef[k] = cT[k];
    #pragma unroll
    for (int k = 0; k < 4; ++k) coef[5 + k] = cD[k];
    #pragma unroll
    for (int k = 0; k < 4; ++k) coef[9 + k] = cR[k];
    coef[13] = rep;

    const int b  = pix / HW;
    const int hw = pix - b * HW;
    float* outp = out + b * (EMB * HW) + hw;

    __syncthreads();   // table ready; coefficient work already done

    // ---- each thread computes 16 channels: e in [16t, 16t+16) ----
    #pragma unroll
    for (int i = 0; i < 4; ++i) {
        const int e0 = t * 16 + i * 4;
        const float4 bv = *reinterpret_cast<const float4*>(&sc[14][e0]);
        float va0 = scalar + bv.x, va1 = scalar + bv.y;
        float va2 = scalar + bv.z, va3 = scalar + bv.w;
        #pragma unroll
        for (int k = 0; k < 14; ++k) {
            const float4 sv = *reinterpret_cast<const float4*>(&sc[k][e0]);
            va0 += coef[k] * sv.x;
            va1 += coef[k] * sv.y;
            va2 += coef[k] * sv.z;
            va3 += coef[k] * sv.w;
        }
        va0 = ((va0 >= 0.f) ? va0 : 0.01f * va0) * ind;
        va1 = ((va1 >= 0.f) ? va1 : 0.01f * va1) * ind;
        va2 = ((va2 >= 0.f) ? va2 : 0.01f * va2) * ind;
        va3 = ((va3 >= 0.f) ? va3 : 0.01f * va3) * ind;
        outp[(e0 + 0) * HW] = va0;
        outp[(e0 + 1) * HW] = va1;
        outp[(e0 + 2) * HW] = va2;
        outp[(e0 + 3) * HW] = va3;
    }
}

extern "C" void kernel_launch(void* const* d_in, const int* in_sizes, int n_in,
                              void* d_out, int out_size, void* d_ws, size_t ws_size,
                              hipStream_t stream) {
    const int*   unit = (const int*)  d_in[0];
    const int*   atp  = (const int*)  d_in[1];
    const int*   dirp = (const int*)  d_in[2];
    const int*   resp = (const int*)  d_in[3];
    const int*   repp = (const int*)  d_in[4];
    const float* amtp = (const float*)d_in[5];
    const float* np_  = (const float*)d_in[6];
    const float* Ttab = (const float*)d_in[7];
    const float* Dtab = (const float*)d_in[8];
    const float* Rtab = (const float*)d_in[9];
    const float* Ptab = (const float*)d_in[10];
    const float* w1p  = (const float*)d_in[11];
    const float* b1p  = (const float*)d_in[12];
    const float* w2p  = (const float*)d_in[13];
    const float* b2p  = (const float*)d_in[14];
    float* out = (float*)d_out;

    act_pre_kernel<<<NBLK, BLOCK, 0, stream>>>(
        unit, atp, dirp, resp, repp, amtp, np_,
        Ttab, Dtab, Rtab, Ptab, w1p, b1p, w2p, b2p, out);
}